// Round 7
// baseline (23476.834 us; speedup 1.0000x reference)
//
#include <hip/hip_runtime.h>

// CfC decoder on MI355X: persistent kernel, 256 blocks x 256 threads (1/CU),
// 128-step scan, flag-array grid barriers.
// Coherence v4 (no L2 invalidation at all):
//  - mutable cross-block buffers: sc1 STORES (write-through MALL) + wide sc1
//    LOADS (global_load_dwordx4 sc1, bypass L2) -> always coherent, no fences.
//  - read-only data (weights/x/h_en/pe): normal cached loads, L2/L1-resident
//    for the entire kernel (never invalidated).
//  - W matrices are read directly from global inside dot loops (L1-cached),
//    NOT staged to LDS: halves LDS instruction count (LDS-BW was the r6 limit).
// fp32 throughout (no fp32 MFMA on CDNA4).

constexpr int BSZ  = 64;
constexpr int LSEQ = 128;
constexpr int TENC = 256;
constexpr int CIN  = 256;
constexpr int HU   = 512;
constexpr int ODIM = 128;
constexpr int NBLK = 256;

typedef float f32x4 __attribute__((ext_vector_type(4)));
typedef unsigned long long ull;

struct Params {
  const float *x, *h_en, *W_dec, *W_enc, *b_enc, *w_score, *W_yattn, *b_yattn;
  const float *W_ih, *b_ih, *W_hh;
  const float *W_ff1, *b_ff1, *W_ff2, *b_ff2, *W_ta, *b_ta, *W_tb, *b_tb;
  const float *W_o1, *b_o1, *W_o2, *b_o2;
  float *out;
  float *pe;        // [B][TENC][HU] proj_enc (cached stores + one wb)
  float *pd_part;   // [8][B][HU]   sc1
  float *e_buf;     // [B][TENC]    sc1
  float *ctx;       // [B][HU]      sc1
  float *xh_part;   // [2][B][CIN]  sc1
  float *hlstm;     // [B][HU]      sc1
  float *h_buf;     // [B][HU]      sc1
  float *c_buf;     // [B][HU]      sc1
  float *hid;       // [B][HU]      sc1
  unsigned *bar;
  unsigned *flags;
};

__device__ __forceinline__ float frcp_(float x) { return __builtin_amdgcn_rcpf(x); }
__device__ __forceinline__ float ftanh_(float x) {
  return 1.0f - 2.0f * frcp_(1.0f + __expf(2.0f * x));
}
__device__ __forceinline__ float fsig_(float x) {
  return frcp_(1.0f + __expf(-x));
}

__device__ __forceinline__ void st_c(float* p, float v) {
  __hip_atomic_store(p, v, __ATOMIC_RELAXED, __HIP_MEMORY_SCOPE_AGENT);
}
__device__ __forceinline__ float ld_a(const float* p) {
  return __hip_atomic_load(p, __ATOMIC_RELAXED, __HIP_MEMORY_SCOPE_AGENT);
}
__device__ __forceinline__ float2 ld_a2(const float* p) {
  union { ull u; float2 f; } c;
  c.u = __hip_atomic_load((const ull*)p, __ATOMIC_RELAXED, __HIP_MEMORY_SCOPE_AGENT);
  return c.f;
}

// 8 coherent 16B loads (bypass L2 via sc1), one batched waitcnt.
__device__ __forceinline__ void sc1_ld8(const float* const (&p)[8], f32x4 (&v)[8]) {
  asm volatile(
    "global_load_dwordx4 %0, %8, off sc1\n\t"
    "global_load_dwordx4 %1, %9, off sc1\n\t"
    "global_load_dwordx4 %2, %10, off sc1\n\t"
    "global_load_dwordx4 %3, %11, off sc1\n\t"
    "global_load_dwordx4 %4, %12, off sc1\n\t"
    "global_load_dwordx4 %5, %13, off sc1\n\t"
    "global_load_dwordx4 %6, %14, off sc1\n\t"
    "global_load_dwordx4 %7, %15, off sc1\n\t"
    "s_waitcnt vmcnt(0)"
    : "=&v"(v[0]), "=&v"(v[1]), "=&v"(v[2]), "=&v"(v[3]),
      "=&v"(v[4]), "=&v"(v[5]), "=&v"(v[6]), "=&v"(v[7])
    : "v"(p[0]), "v"(p[1]), "v"(p[2]), "v"(p[3]),
      "v"(p[4]), "v"(p[5]), "v"(p[6]), "v"(p[7])
    : "memory");
  __builtin_amdgcn_sched_barrier(0);
}

// Flag-array grid barrier, all relaxed, NO acquire fence (no L2 data to
// invalidate: mutable data is read via sc1). Producer drain via waitcnt.
__device__ __forceinline__ void gridbar(unsigned* bar, unsigned* flags, unsigned gen) {
  __syncthreads();
  const int t = threadIdx.x;
  if (t == 0) {
    asm volatile("s_waitcnt vmcnt(0) lgkmcnt(0)" ::: "memory");
    __hip_atomic_store(flags + blockIdx.x * 16, gen,
                       __ATOMIC_RELAXED, __HIP_MEMORY_SCOPE_AGENT);
  }
  if (blockIdx.x == 0) {
    while (__hip_atomic_load(flags + t * 16, __ATOMIC_RELAXED,
                             __HIP_MEMORY_SCOPE_AGENT) < gen)
      __builtin_amdgcn_s_sleep(1);
    __syncthreads();
    if (t == 0)
      __hip_atomic_store(bar, gen, __ATOMIC_RELAXED, __HIP_MEMORY_SCOPE_AGENT);
  }
  if (t == 0) {
    while (__hip_atomic_load(bar, __ATOMIC_RELAXED,
                             __HIP_MEMORY_SCOPE_AGENT) < gen)
      __builtin_amdgcn_s_sleep(1);
  }
  __syncthreads();
}

// ---- dot helpers: A from LDS, W directly from global (L1/L2-cached) ----
__device__ __forceinline__ void dotg2x2(const float* A0, const float* A1,
                                        const float* W0, const float* W1,
                                        int nk4, float (&acc)[2][2]) {
#pragma unroll 8
  for (int k4 = 0; k4 < nk4; ++k4) {
    float4 w0 = *(const float4*)(W0 + (k4 << 2));
    float4 w1 = *(const float4*)(W1 + (k4 << 2));
    float4 a0 = *(const float4*)(A0 + (k4 << 2));
    float4 a1 = *(const float4*)(A1 + (k4 << 2));
    acc[0][0] = fmaf(a0.x, w0.x, acc[0][0]); acc[0][0] = fmaf(a0.y, w0.y, acc[0][0]);
    acc[0][0] = fmaf(a0.z, w0.z, acc[0][0]); acc[0][0] = fmaf(a0.w, w0.w, acc[0][0]);
    acc[0][1] = fmaf(a0.x, w1.x, acc[0][1]); acc[0][1] = fmaf(a0.y, w1.y, acc[0][1]);
    acc[0][1] = fmaf(a0.z, w1.z, acc[0][1]); acc[0][1] = fmaf(a0.w, w1.w, acc[0][1]);
    acc[1][0] = fmaf(a1.x, w0.x, acc[1][0]); acc[1][0] = fmaf(a1.y, w0.y, acc[1][0]);
    acc[1][0] = fmaf(a1.z, w0.z, acc[1][0]); acc[1][0] = fmaf(a1.w, w0.w, acc[1][0]);
    acc[1][1] = fmaf(a1.x, w1.x, acc[1][1]); acc[1][1] = fmaf(a1.y, w1.y, acc[1][1]);
    acc[1][1] = fmaf(a1.z, w1.z, acc[1][1]); acc[1][1] = fmaf(a1.w, w1.w, acc[1][1]);
  }
}

__device__ __forceinline__ void dotg1x2(const float* A0,
                                        const float* W0, const float* W1,
                                        int nk4, float (&acc)[2]) {
#pragma unroll 8
  for (int k4 = 0; k4 < nk4; ++k4) {
    float4 w0 = *(const float4*)(W0 + (k4 << 2));
    float4 w1 = *(const float4*)(W1 + (k4 << 2));
    float4 a  = *(const float4*)(A0 + (k4 << 2));
    acc[0] = fmaf(a.x, w0.x, acc[0]); acc[0] = fmaf(a.y, w0.y, acc[0]);
    acc[0] = fmaf(a.z, w0.z, acc[0]); acc[0] = fmaf(a.w, w0.w, acc[0]);
    acc[1] = fmaf(a.x, w1.x, acc[1]); acc[1] = fmaf(a.y, w1.y, acc[1]);
    acc[1] = fmaf(a.z, w1.z, acc[1]); acc[1] = fmaf(a.w, w1.w, acc[1]);
  }
}

__device__ __forceinline__ void dotg2x4(const float* A0, const float* A1,
                                        const float* W0, const float* W1,
                                        const float* W2, const float* W3,
                                        int nk4, float (&acc)[2][4]) {
#pragma unroll 4
  for (int k4 = 0; k4 < nk4; ++k4) {
    float4 w0 = *(const float4*)(W0 + (k4 << 2));
    float4 w1 = *(const float4*)(W1 + (k4 << 2));
    float4 w2 = *(const float4*)(W2 + (k4 << 2));
    float4 w3 = *(const float4*)(W3 + (k4 << 2));
#pragma unroll
    for (int i = 0; i < 2; ++i) {
      float4 a = *(const float4*)((i ? A1 : A0) + (k4 << 2));
      acc[i][0] = fmaf(a.x, w0.x, acc[i][0]); acc[i][0] = fmaf(a.y, w0.y, acc[i][0]);
      acc[i][0] = fmaf(a.z, w0.z, acc[i][0]); acc[i][0] = fmaf(a.w, w0.w, acc[i][0]);
      acc[i][1] = fmaf(a.x, w1.x, acc[i][1]); acc[i][1] = fmaf(a.y, w1.y, acc[i][1]);
      acc[i][1] = fmaf(a.z, w1.z, acc[i][1]); acc[i][1] = fmaf(a.w, w1.w, acc[i][1]);
      acc[i][2] = fmaf(a.x, w2.x, acc[i][2]); acc[i][2] = fmaf(a.y, w2.y, acc[i][2]);
      acc[i][2] = fmaf(a.z, w2.z, acc[i][2]); acc[i][2] = fmaf(a.w, w2.w, acc[i][2]);
      acc[i][3] = fmaf(a.x, w3.x, acc[i][3]); acc[i][3] = fmaf(a.y, w3.y, acc[i][3]);
      acc[i][3] = fmaf(a.z, w3.z, acc[i][3]); acc[i][3] = fmaf(a.w, w3.w, acc[i][3]);
    }
  }
}

__launch_bounds__(256)
__global__ void cfc_kernel(Params P) {
  __shared__ float lds[8448];           // A tiles only (33.8 KB)
  __shared__ const float* wrA[32];
  __shared__ const float* wrB[16];
  __shared__ float biasS[32];

  const int t = threadIdx.x;
  unsigned gen = 1;

  // ---------- P0: proj_enc (16384x512, K=512) + zero h/c ----------
  for (int job = blockIdx.x; job < 4096 + 32; job += NBLK) {
    if (job < 4096) {
      int rt = job & 255, ct = job >> 8;
      if (t < 32) {
        wrA[t] = P.W_enc + (ct * 32 + t) * HU;
        biasS[t] = P.b_enc[ct * 32 + t];
      }
      const int c0 = (t & 7) * 4, b0 = (t >> 3) * 2;
      __syncthreads();
      float acc[2][4];
#pragma unroll
      for (int i = 0; i < 2; ++i)
#pragma unroll
        for (int j = 0; j < 4; ++j) acc[i][j] = biasS[c0 + j];
      const float* Ab = P.h_en + (size_t)(rt * 64) * HU;
      const float* W0 = wrA[c0], *W1 = wrA[c0 + 1], *W2 = wrA[c0 + 2], *W3 = wrA[c0 + 3];
      for (int s = 0; s < 4; ++s) {
        int ko = s * 128;
#pragma unroll
        for (int i = 0; i < 8; ++i) {
          int idx = t + i * 256; int r = idx >> 5, c4 = idx & 31;
          *(float4*)&lds[r * 132 + (c4 << 2)] =
            *(const float4*)(Ab + (size_t)r * HU + ko + (c4 << 2));
        }
        __syncthreads();
        dotg2x4(&lds[b0 * 132], &lds[(b0 + 1) * 132],
                W0 + ko, W1 + ko, W2 + ko, W3 + ko, 32, acc);
        __syncthreads();
      }
      float* outp = P.pe + (size_t)(rt * 64) * HU + ct * 32;
#pragma unroll
      for (int i = 0; i < 2; ++i)
#pragma unroll
        for (int j = 0; j < 4; ++j)
          outp[(b0 + i) * HU + c0 + j] = acc[i][j];
    } else {
      int idx = job - 4096;
      float* base = (idx < 16 ? P.h_buf : P.c_buf) + (idx & 15) * 2048;
      for (int i = t; i < 2048; i += 256) st_c(base + i, 0.f);
    }
  }
  // push pe's dirty L2 lines to MALL once (readers cache it clean afterwards)
  __builtin_amdgcn_fence(__ATOMIC_RELEASE, "agent");
  gridbar(P.bar, P.flags, gen++);

  // ---------- scan over 128 steps ----------
  for (int step = 0; step < LSEQ; ++step) {

    // --- A: proj_dec partials. 32 col-tiles x 8 K-splits (K=128).
    {
      int ut = blockIdx.x & 31, ks = blockIdx.x >> 5;
      if (t < 16) wrA[t] = P.W_dec + (ut * 16 + t) * 1024 + ks * 128;
      const int c0 = (t & 7) * 2, b0 = (t >> 3) * 2;
      const float* Asrc = (ks < 4) ? (P.h_buf + ks * 128) : (P.c_buf + (ks - 4) * 128);
      __syncthreads();
      {
        const float* p[8]; f32x4 v[8];
#pragma unroll
        for (int i = 0; i < 8; ++i) {
          int idx = t + i * 256; int r = idx >> 5, c4 = idx & 31;
          p[i] = Asrc + r * HU + (c4 << 2);
        }
        sc1_ld8(p, v);
#pragma unroll
        for (int i = 0; i < 8; ++i) {
          int idx = t + i * 256; int r = idx >> 5, c4 = idx & 31;
          *(f32x4*)&lds[r * 132 + (c4 << 2)] = v[i];
        }
      }
      __syncthreads();
      float acc[2][2] = {{0.f, 0.f}, {0.f, 0.f}};
      dotg2x2(&lds[b0 * 132], &lds[(b0 + 1) * 132], wrA[c0], wrA[c0 + 1], 32, acc);
      float* outp = P.pd_part + ks * (BSZ * HU) + ut * 16;
      st_c(outp + b0 * HU + c0,           acc[0][0]);
      st_c(outp + b0 * HU + c0 + 1,       acc[0][1]);
      st_c(outp + (b0 + 1) * HU + c0,     acc[1][0]);
      st_c(outp + (b0 + 1) * HU + c0 + 1, acc[1][1]);
    }
    gridbar(P.bar, P.flags, gen++);

    // --- B1: attention logits. 64 b x 4 t-quarters. pe stays L2-cached.
    {
      int b = blockIdx.x >> 2, tq = blockIdx.x & 3;
      float* pds = lds;         // [516] skewed
      float* wsc = lds + 520;   // [516] skewed
      __syncthreads();
      {
        int h = t * 2;
        float sx = 0.f, sy = 0.f;
#pragma unroll
        for (int p8 = 0; p8 < 8; ++p8) {
          float2 v = ld_a2(P.pd_part + p8 * (BSZ * HU) + b * HU + h);
          sx += v.x; sy += v.y;
        }
        int hs = h + (h >> 7);
        pds[hs] = sx; pds[hs + 1] = sy;
        float2 w = *(const float2*)(P.w_score + h);
        wsc[hs] = w.x; wsc[hs + 1] = w.y;
      }
      __syncthreads();
      int q = t & 3, tt = tq * 64 + (t >> 2);
      const float* per = P.pe + (size_t)(b * TENC + tt) * HU + q * 128;
      const float* pd = pds + q * 129;
      const float* wv = wsc + q * 129;
      float acc = 0.f;
      for (int h4 = 0; h4 < 32; ++h4) {
        float4 pv = *(const float4*)(per + (h4 << 2));
        int o = h4 << 2;
        acc += wv[o + 0] * ftanh_(pd[o + 0] + pv.x);
        acc += wv[o + 1] * ftanh_(pd[o + 1] + pv.y);
        acc += wv[o + 2] * ftanh_(pd[o + 2] + pv.z);
        acc += wv[o + 3] * ftanh_(pd[o + 3] + pv.w);
      }
      acc += __shfl_xor(acc, 1);
      acc += __shfl_xor(acc, 2);
      if (q == 0) st_c(P.e_buf + b * TENC + tt, acc);
    }
    gridbar(P.bar, P.flags, gen++);

    // --- B2: softmax (x4 redundant) + context slice. 64 b x 4 m-quarters.
    {
      int b = blockIdx.x >> 2, mq = blockIdx.x & 3;
      float* es = lds;          // [256]
      float* red = lds + 260;   // [8]
      float v = ld_a(P.e_buf + b * TENC + t);
      float m = v;
#pragma unroll
      for (int o = 1; o < 64; o <<= 1) m = fmaxf(m, __shfl_xor(m, o));
      int wid = t >> 6;
      if ((t & 63) == 0) red[wid] = m;
      __syncthreads();
      m = fmaxf(fmaxf(red[0], red[1]), fmaxf(red[2], red[3]));
      float p = __expf(v - m);
      float s = p;
#pragma unroll
      for (int o = 1; o < 64; o <<= 1) s += __shfl_xor(s, o);
      if ((t & 63) == 0) red[4 + wid] = s;
      __syncthreads();
      float sum = (red[4] + red[5]) + (red[6] + red[7]);
      es[t] = p * frcp_(sum);
      __syncthreads();
      if (t < 128) {
        int mcol = mq * 128 + t;
        const float* hb = P.h_en + (size_t)b * TENC * HU + mcol;
        float a0 = 0.f, a1 = 0.f, a2 = 0.f, a3 = 0.f;
        for (int tt = 0; tt < TENC; tt += 4) {
          a0 = fmaf(es[tt + 0], hb[(tt + 0) * HU], a0);
          a1 = fmaf(es[tt + 1], hb[(tt + 1) * HU], a1);
          a2 = fmaf(es[tt + 2], hb[(tt + 2) * HU], a2);
          a3 = fmaf(es[tt + 3], hb[(tt + 3) * HU], a3);
        }
        st_c(P.ctx + b * HU + mcol, (a0 + a1) + (a2 + a3));
      }
    }
    gridbar(P.bar, P.flags, gen++);

    // --- C: x_hat partials. 32 jobs = 16 col-tiles x 2 K-splits (3x128 each).
    if (blockIdx.x < 32) {
      int ct = blockIdx.x & 15, ks = blockIdx.x >> 4;
      if (t < 16) {
        wrA[t] = P.W_yattn + (ct * 16 + t) * 768 + ks * 384;
        biasS[t] = ks ? 0.f : P.b_yattn[ct * 16 + t];
      }
      const int c0 = (t & 7) * 2, b0 = (t >> 3) * 2;
      __syncthreads();
      float acc[2][2];
      acc[0][0] = biasS[c0]; acc[0][1] = biasS[c0 + 1];
      acc[1][0] = biasS[c0]; acc[1][1] = biasS[c0 + 1];
      const float* W0 = wrA[c0], *W1 = wrA[c0 + 1];
      for (int s = 0; s < 3; ++s) {
        int k = ks * 384 + s * 128;
        if (k < 256) {  // x: read-only, cached
#pragma unroll
          for (int i = 0; i < 8; ++i) {
            int idx = t + i * 256; int r = idx >> 5, c4 = idx & 31;
            *(float4*)&lds[r * 132 + (c4 << 2)] =
              *(const float4*)(P.x + ((size_t)r * LSEQ + step) * CIN + k + (c4 << 2));
          }
        } else {        // ctx: mutable, sc1
          const float* p[8]; f32x4 v[8];
#pragma unroll
          for (int i = 0; i < 8; ++i) {
            int idx = t + i * 256; int r = idx >> 5, c4 = idx & 31;
            p[i] = P.ctx + r * HU + (k - 256) + (c4 << 2);
          }
          sc1_ld8(p, v);
#pragma unroll
          for (int i = 0; i < 8; ++i) {
            int idx = t + i * 256; int r = idx >> 5, c4 = idx & 31;
            *(f32x4*)&lds[r * 132 + (c4 << 2)] = v[i];
          }
        }
        __syncthreads();
        dotg2x2(&lds[b0 * 132], &lds[(b0 + 1) * 132],
                W0 + s * 128, W1 + s * 128, 32, acc);
        __syncthreads();
      }
      float* outp = P.xh_part + ks * (BSZ * CIN) + ct * 16;
      st_c(outp + b0 * CIN + c0,           acc[0][0]);
      st_c(outp + b0 * CIN + c0 + 1,       acc[0][1]);
      st_c(outp + (b0 + 1) * CIN + c0,     acc[1][0]);
      st_c(outp + (b0 + 1) * CIN + c0 + 1, acc[1][1]);
    }
    gridbar(P.bar, P.flags, gen++);

    // --- D: LSTM gates + elementwise. 256 jobs, 32x16 tiles, K=768 (3x256).
    {
      int bt = blockIdx.x & 1, jq = blockIdx.x >> 1;
      int j0 = jq * 4, rowbase = bt * 32;
      if (t < 16) {
        int jj = t >> 2, g = t & 3;
        int r = g * 512 + j0 + jj;
        wrA[t] = P.W_ih + r * 256;
        wrB[t] = P.W_hh + (size_t)r * 512;
        biasS[t] = P.b_ih[r];
      }
      const int c0 = (t & 7) * 2, b0 = t >> 3;
      __syncthreads();
      float acc[2];
      acc[0] = biasS[c0]; acc[1] = biasS[c0 + 1];
      for (int s = 0; s < 3; ++s) {
        if (s == 0) {  // A = x_hat = part0 + part1 (sc1)
          const float* p[8]; f32x4 v[8], v2[8];
#pragma unroll
          for (int i = 0; i < 8; ++i) {
            int idx = t + i * 256; int r = idx >> 6, c4 = idx & 63;
            p[i] = P.xh_part + (rowbase + r) * CIN + (c4 << 2);
          }
          sc1_ld8(p, v);
#pragma unroll
          for (int i = 0; i < 8; ++i) p[i] += BSZ * CIN;
          sc1_ld8(p, v2);
#pragma unroll
          for (int i = 0; i < 8; ++i) {
            int idx = t + i * 256; int r = idx >> 6, c4 = idx & 63;
            *(f32x4*)&lds[r * 260 + (c4 << 2)] = v[i] + v2[i];
          }
        } else {       // A = h_buf slice (sc1)
          int ho = (s - 1) * 256;
          const float* p[8]; f32x4 v[8];
#pragma unroll
          for (int i = 0; i < 8; ++i) {
            int idx = t + i * 256; int r = idx >> 6, c4 = idx & 63;
            p[i] = P.h_buf + (rowbase + r) * HU + ho + (c4 << 2);
          }
          sc1_ld8(p, v);
#pragma unroll
          for (int i = 0; i < 8; ++i) {
            int idx = t + i * 256; int r = idx >> 6, c4 = idx & 63;
            *(f32x4*)&lds[r * 260 + (c4 << 2)] = v[i];
          }
        }
        __syncthreads();
        const float* W0 = (s == 0) ? wrA[c0]     : wrB[c0] + (s - 1) * 256;
        const float* W1 = (s == 0) ? wrA[c0 + 1] : wrB[c0 + 1] + (s - 1) * 256;
        dotg1x2(&lds[b0 * 260], W0, W1, 64, acc);
        __syncthreads();
      }
      float* zs = lds;
      zs[b0 * 16 + c0] = acc[0];
      zs[b0 * 16 + c0 + 1] = acc[1];
      __syncthreads();
      if (t < 128) {
        int b2 = t >> 2, jj = t & 3;
        int gb = rowbase + b2, j = j0 + jj;
        float i_ = zs[b2 * 16 + jj * 4 + 0];
        float ig = zs[b2 * 16 + jj * 4 + 1];
        float fg = zs[b2 * 16 + jj * 4 + 2];
        float og = zs[b2 * 16 + jj * 4 + 3];
        float cold = ld_a(P.c_buf + gb * HU + j);
        float cn = cold * fsig_(fg + 1.0f) + ftanh_(i_) * fsig_(ig);
        st_c(P.c_buf + gb * HU + j, cn);
        st_c(P.hlstm + gb * HU + j, ftanh_(cn) * fsig_(og));
      }
    }
    gridbar(P.bar, P.flags, gen++);

    // --- E: CfC ff1/ff2/ta/tb + combine. 256 jobs, 32x16, K=768 (3x256).
    {
      int bt = blockIdx.x & 1, jq = blockIdx.x >> 1;
      int j0 = jq * 4, rowbase = bt * 32;
      if (t < 16) {
        int jj = t >> 2, m = t & 3;
        const float* Wm = (m == 0) ? P.W_ff1 : (m == 1) ? P.W_ff2 : (m == 2) ? P.W_ta : P.W_tb;
        const float* bm = (m == 0) ? P.b_ff1 : (m == 1) ? P.b_ff2 : (m == 2) ? P.b_ta : P.b_tb;
        wrA[t] = Wm + (j0 + jj) * 768;
        biasS[t] = bm[j0 + jj];
      }
      const int c0 = (t & 7) * 2, b0 = t >> 3;
      __syncthreads();
      float acc[2];
      acc[0] = biasS[c0]; acc[1] = biasS[c0 + 1];
      for (int s = 0; s < 3; ++s) {
        if (s == 0) {
          const float* p[8]; f32x4 v[8], v2[8];
#pragma unroll
          for (int i = 0; i < 8; ++i) {
            int idx = t + i * 256; int r = idx >> 6, c4 = idx & 63;
            p[i] = P.xh_part + (rowbase + r) * CIN + (c4 << 2);
          }
          sc1_ld8(p, v);
#pragma unroll
          for (int i = 0; i < 8; ++i) p[i] += BSZ * CIN;
          sc1_ld8(p, v2);
#pragma unroll
          for (int i = 0; i < 8; ++i) {
            int idx = t + i * 256; int r = idx >> 6, c4 = idx & 63;
            *(f32x4*)&lds[r * 260 + (c4 << 2)] = v[i] + v2[i];
          }
        } else {
          int ho = (s - 1) * 256;
          const float* p[8]; f32x4 v[8];
#pragma unroll
          for (int i = 0; i < 8; ++i) {
            int idx = t + i * 256; int r = idx >> 6, c4 = idx & 63;
            p[i] = P.hlstm + (rowbase + r) * HU + ho + (c4 << 2);
          }
          sc1_ld8(p, v);
#pragma unroll
          for (int i = 0; i < 8; ++i) {
            int idx = t + i * 256; int r = idx >> 6, c4 = idx & 63;
            *(f32x4*)&lds[r * 260 + (c4 << 2)] = v[i];
          }
        }
        __syncthreads();
        dotg1x2(&lds[b0 * 260], wrA[c0] + s * 256, wrA[c0 + 1] + s * 256, 64, acc);
        __syncthreads();
      }
      float* es2 = lds;
      es2[b0 * 16 + c0] = acc[0];
      es2[b0 * 16 + c0 + 1] = acc[1];
      __syncthreads();
      if (t < 128) {
        int b2 = t >> 2, jj = t & 3;
        int gb = rowbase + b2, j = j0 + jj;
        float ff1 = ftanh_(es2[b2 * 16 + jj * 4 + 0]);
        float ff2 = ftanh_(es2[b2 * 16 + jj * 4 + 1]);
        float ta  = es2[b2 * 16 + jj * 4 + 2];
        float tb  = es2[b2 * 16 + jj * 4 + 3];
        float ti = fsig_(ta + tb);  // ts = 1.0
        st_c(P.h_buf + gb * HU + j, ff1 * (1.0f - ti) + ti * ff2);
      }
    }
    gridbar(P.bar, P.flags, gen++);
  }

  // ---------- F1: hid = leaky_relu([h|ctx] @ W_o1^T + b). 64 jobs, 32x16 ----------
  if (blockIdx.x < 64) {
    int bt = blockIdx.x & 1, ut = blockIdx.x >> 1;
    int rowbase = bt * 32;
    if (t < 16) {
      wrA[t] = P.W_o1 + (ut * 16 + t) * 1024;
      biasS[t] = P.b_o1[ut * 16 + t];
    }
    const int c0 = (t & 7) * 2, b0 = t >> 3;
    __syncthreads();
    float acc[2];
    acc[0] = biasS[c0]; acc[1] = biasS[c0 + 1];
    for (int s = 0; s < 4; ++s) {
      const float* src = (s < 2) ? (P.h_buf + s * 256) : (P.ctx + (s - 2) * 256);
      const float* p[8]; f32x4 v[8];
#pragma unroll
      for (int i = 0; i < 8; ++i) {
        int idx = t + i * 256; int r = idx >> 6, c4 = idx & 63;
        p[i] = src + (rowbase + r) * HU + (c4 << 2);
      }
      sc1_ld8(p, v);
#pragma unroll
      for (int i = 0; i < 8; ++i) {
        int idx = t + i * 256; int r = idx >> 6, c4 = idx & 63;
        *(f32x4*)&lds[r * 260 + (c4 << 2)] = v[i];
      }
      __syncthreads();
      dotg1x2(&lds[b0 * 260], wrA[c0] + s * 256, wrA[c0 + 1] + s * 256, 64, acc);
      __syncthreads();
    }
#pragma unroll
    for (int j = 0; j < 2; ++j) {
      float v2 = acc[j];
      st_c(P.hid + (rowbase + b0) * HU + ut * 16 + c0 + j, v2 > 0.f ? v2 : 0.01f * v2);
    }
  }
  gridbar(P.bar, P.flags, gen++);

  // ---------- F2: out = hid @ W_o2^T + b (16 jobs) + state copies ----------
  {
    int job = blockIdx.x;
    if (job < 16) {
      int bt = job & 1, ot = job >> 1;
      int rowbase = bt * 32;
      if (t < 16) {
        wrA[t] = P.W_o2 + (ot * 16 + t) * HU;
        biasS[t] = P.b_o2[ot * 16 + t];
      }
      const int c0 = (t & 7) * 2, b0 = t >> 3;
      __syncthreads();
      float acc[2];
      acc[0] = biasS[c0]; acc[1] = biasS[c0 + 1];
      for (int s = 0; s < 2; ++s) {
        const float* p[8]; f32x4 v[8];
#pragma unroll
        for (int i = 0; i < 8; ++i) {
          int idx = t + i * 256; int r = idx >> 6, c4 = idx & 63;
          p[i] = P.hid + (rowbase + r) * HU + s * 256 + (c4 << 2);
        }
        sc1_ld8(p, v);
#pragma unroll
        for (int i = 0; i < 8; ++i) {
          int idx = t + i * 256; int r = idx >> 6, c4 = idx & 63;
          *(f32x4*)&lds[r * 260 + (c4 << 2)] = v[i];
        }
        __syncthreads();
        dotg1x2(&lds[b0 * 260], wrA[c0] + s * 256, wrA[c0 + 1] + s * 256, 64, acc);
        __syncthreads();
      }
      P.out[(rowbase + b0) * ODIM + ot * 16 + c0]     = acc[0];
      P.out[(rowbase + b0) * ODIM + ot * 16 + c0 + 1] = acc[1];
    } else if (job < 48) {
      int idx = job - 16;
      const float* src = (idx < 16 ? P.h_buf : P.c_buf) + (idx & 15) * 2048;
      float* dst = P.out + BSZ * ODIM + (idx < 16 ? 0 : BSZ * HU) + (idx & 15) * 2048;
      for (int i = t; i < 512; i += 256) {
        const float* p[8]; f32x4 v[8];
        // 512 float4s / 256 threads = 2 per thread; do as 2 singles via ld_a2x2
        (void)p; (void)v;
      }
      for (int i = t; i < 1024; i += 256) {
        float2 f = ld_a2(src + 2 * i);
        *(float2*)(dst + 2 * i) = f;
      }
    }
  }
}

extern "C" void kernel_launch(void* const* d_in, const int* in_sizes, int n_in,
                              void* d_out, int out_size, void* d_ws, size_t ws_size,
                              hipStream_t stream) {
  (void)in_sizes; (void)n_in; (void)out_size; (void)ws_size;
  Params P;
  P.x       = (const float*)d_in[0];
  P.h_en    = (const float*)d_in[1];
  P.W_dec   = (const float*)d_in[2];
  P.W_enc   = (const float*)d_in[3];
  P.b_enc   = (const float*)d_in[4];
  P.w_score = (const float*)d_in[5];
  P.W_yattn = (const float*)d_in[6];
  P.b_yattn = (const float*)d_in[7];
  P.W_ih    = (const float*)d_in[8];
  P.b_ih    = (const float*)d_in[9];
  P.W_hh    = (const float*)d_in[10];
  P.W_ff1   = (const float*)d_in[11];
  P.b_ff1   = (const float*)d_in[12];
  P.W_ff2   = (const float*)d_in[13];
  P.b_ff2   = (const float*)d_in[14];
  P.W_ta    = (const float*)d_in[15];
  P.b_ta    = (const float*)d_in[16];
  P.W_tb    = (const float*)d_in[17];
  P.b_tb    = (const float*)d_in[18];
  P.W_o1    = (const float*)d_in[19];
  P.b_o1    = (const float*)d_in[20];
  P.W_o2    = (const float*)d_in[21];
  P.b_o2    = (const float*)d_in[22];
  P.out     = (float*)d_out;

  float* ws = (float*)d_ws;
  size_t off = 0;
  P.pe      = ws + off; off += (size_t)BSZ * TENC * HU;
  P.pd_part = ws + off; off += (size_t)8 * BSZ * HU;
  P.e_buf   = ws + off; off += (size_t)BSZ * TENC;
  P.ctx     = ws + off; off += (size_t)BSZ * HU;
  P.xh_part = ws + off; off += (size_t)2 * BSZ * CIN;
  P.hlstm   = ws + off; off += (size_t)BSZ * HU;
  P.h_buf   = ws + off; off += (size_t)BSZ * HU;
  P.c_buf   = ws + off; off += (size_t)BSZ * HU;
  P.hid     = ws + off; off += (size_t)BSZ * HU;
  P.bar     = (unsigned*)(ws + off); off += 16;
  P.flags   = (unsigned*)(ws + off);

  (void)hipMemsetAsync((void*)P.bar, 0, 64 + 256 * 64, stream);

  hipLaunchKernelGGL(cfc_kernel, dim3(NBLK), dim3(256), 0, stream, P);
}